// Round 1
// baseline (298.609 us; speedup 1.0000x reference)
//
#include <hip/hip_runtime.h>
#include <hip/hip_bf16.h>

typedef __bf16 bf16_t;
typedef __bf16 bf16x8 __attribute__((ext_vector_type(8)));
typedef __bf16 bf16x4 __attribute__((ext_vector_type(4)));
typedef float f32x4 __attribute__((ext_vector_type(4)));

#define M_TOK 128
#define K_IN 4096
#define N_OUT 11008
#define R_LORA 16
#define SCALING 2.0f

// ---------------------------------------------------------------------------
// Kernel A: x (fp32) -> x_bf16 in ws, and T = (x @ lora_A^T) * SCALING in ws.
// One block per token row m. 256 threads.
// ---------------------------------------------------------------------------
__global__ __launch_bounds__(256) void k_prep(const float* __restrict__ x,
                                              const float* __restrict__ loraA,
                                              float* __restrict__ T,
                                              bf16_t* __restrict__ xb) {
  const int m = blockIdx.x;
  __shared__ float xs[K_IN];
  const float4* xr = (const float4*)(x + (size_t)m * K_IN);
  bf16x4* xbr = (bf16x4*)(xb + (size_t)m * K_IN);
  for (int i = threadIdx.x; i < K_IN / 4; i += 256) {
    float4 v = xr[i];
    ((float4*)xs)[i] = v;
    bf16x4 pv = {(bf16_t)v.x, (bf16_t)v.y, (bf16_t)v.z, (bf16_t)v.w};
    xbr[i] = pv;
  }
  __syncthreads();
  const int w = threadIdx.x >> 6;
  const int lane = threadIdx.x & 63;
  float a0 = 0.f, a1 = 0.f, a2 = 0.f, a3 = 0.f;
  const float4* A0 = (const float4*)(loraA + (size_t)(w * 4 + 0) * K_IN);
  const float4* A1 = (const float4*)(loraA + (size_t)(w * 4 + 1) * K_IN);
  const float4* A2 = (const float4*)(loraA + (size_t)(w * 4 + 2) * K_IN);
  const float4* A3 = (const float4*)(loraA + (size_t)(w * 4 + 3) * K_IN);
  for (int i = lane; i < K_IN / 4; i += 64) {
    float4 xv = ((float4*)xs)[i];
    float4 v0 = A0[i], v1 = A1[i], v2 = A2[i], v3 = A3[i];
    a0 += xv.x * v0.x + xv.y * v0.y + xv.z * v0.z + xv.w * v0.w;
    a1 += xv.x * v1.x + xv.y * v1.y + xv.z * v1.z + xv.w * v1.w;
    a2 += xv.x * v2.x + xv.y * v2.y + xv.z * v2.z + xv.w * v2.w;
    a3 += xv.x * v3.x + xv.y * v3.y + xv.z * v3.z + xv.w * v3.w;
  }
#pragma unroll
  for (int off = 32; off; off >>= 1) {
    a0 += __shfl_down(a0, off);
    a1 += __shfl_down(a1, off);
    a2 += __shfl_down(a2, off);
    a3 += __shfl_down(a3, off);
  }
  if (lane == 0) {
    float* tm = T + m * R_LORA + w * 4;
    tm[0] = a0 * SCALING;
    tm[1] = a1 * SCALING;
    tm[2] = a2 * SCALING;
    tm[3] = a3 * SCALING;
  }
}

// ---------------------------------------------------------------------------
// Kernel B: out = T @ lora_B^T  (full overwrite of d_out -> handles poison).
// grid 128*43 = 5504 blocks, 256 threads; 43*256 == 11008 exactly.
// ---------------------------------------------------------------------------
__global__ __launch_bounds__(256) void k_lora(const float* __restrict__ T,
                                              const float* __restrict__ loraB,
                                              float* __restrict__ out) {
  const int b = blockIdx.x;
  const int m = b / 43;
  const int o = (b % 43) * 256 + threadIdx.x;
  const float* t = T + m * R_LORA;
  const float4* br = (const float4*)(loraB + (size_t)o * R_LORA);
  float4 b0 = br[0], b1 = br[1], b2 = br[2], b3 = br[3];
  float s = t[0] * b0.x + t[1] * b0.y + t[2] * b0.z + t[3] * b0.w +
            t[4] * b1.x + t[5] * b1.y + t[6] * b1.z + t[7] * b1.w +
            t[8] * b2.x + t[9] * b2.y + t[10] * b2.z + t[11] * b2.w +
            t[12] * b3.x + t[13] * b3.y + t[14] * b3.z + t[15] * b3.w;
  out[(size_t)m * N_OUT + o] = s;
}

// ---------------------------------------------------------------------------
// Kernel C: main dequant GEMM. 172 N-strips (64 cols) x 4 K-chunks (1024).
// Per block: 128x64 partial tile, atomically added into out.
// LDS tile: W_lds[o][k], o-stride 56 bf16 = 112 B (16B-aligned, bank-even).
// ---------------------------------------------------------------------------
#define NSTRIPS 172
#define WSTRIDE 56  // bf16 elements per o-row in LDS (112 bytes)

__global__ __launch_bounds__(256) void k_main(const int* __restrict__ qw,
                                              const int* __restrict__ zr,
                                              const float* __restrict__ sc,
                                              const bf16_t* __restrict__ xb,
                                              float* __restrict__ out) {
  const int nb = blockIdx.x % NSTRIPS;
  const int kc = blockIdx.x / NSTRIPS;  // 0..3
  const int o0 = nb * 64;
  const int k0 = kc * 1024;

  __shared__ __align__(16) bf16_t wlds[2][64 * WSTRIDE];

  const int tid = threadIdx.x;
  const int w = tid >> 6;
  const int lane = tid & 63;

  // staging role: thread covers o = o0 + (tid&63), k-octet base kq = (wave)*8
  const int oq = tid & 63;
  const int kq = w * 8;
  const int ocol = o0 + oq;
  const int* qp = qw + (size_t)(k0 + kq) * N_OUT + ocol;

  // per-group dequant params for this thread's column
  float sf, nzs;
  {
    const int g0 = k0 >> 7;
    float s_ = sc[(size_t)g0 * N_OUT + ocol];
    int z_ = zr[(size_t)g0 * N_OUT + ocol];
    sf = s_;
    nzs = -(float)z_ * s_;
  }

  int qr[8];
#pragma unroll
  for (int j = 0; j < 8; ++j) qr[j] = qp[(size_t)j * N_OUT];
  {
    bf16x8 wv;
#pragma unroll
    for (int j = 0; j < 8; ++j) wv[j] = (bf16_t)fmaf((float)qr[j], sf, nzs);
    *(bf16x8*)&wlds[0][oq * WSTRIDE + kq] = wv;
  }

  f32x4 acc[2][4];
#pragma unroll
  for (int mt = 0; mt < 2; ++mt)
#pragma unroll
    for (int ot = 0; ot < 4; ++ot) acc[mt][ot] = (f32x4){0.f, 0.f, 0.f, 0.f};

  // MFMA A-operand: lane holds A[m = lane&15][k = (lane>>4)*8 + j]
  const int aq = (lane >> 4) * 8;
  const bf16_t* ap = xb + (size_t)(w * 32 + (lane & 15)) * K_IN + k0 + aq;

  for (int step = 0; step < 32; ++step) {
    __syncthreads();
    const int buf = step & 1;

    if (step + 1 < 32) {
      const int* qn = qp + (size_t)(step + 1) * 32 * N_OUT;
#pragma unroll
      for (int j = 0; j < 8; ++j) qr[j] = qn[(size_t)j * N_OUT];
      if (((step + 1) & 3) == 0) {
        const int g = (k0 >> 7) + ((step + 1) >> 2);
        float s_ = sc[(size_t)g * N_OUT + ocol];
        int z_ = zr[(size_t)g * N_OUT + ocol];
        sf = s_;
        nzs = -(float)z_ * s_;
      }
    }

    bf16x8 a0 = *(const bf16x8*)(ap + step * 32);
    bf16x8 a1 = *(const bf16x8*)(ap + (size_t)16 * K_IN + step * 32);

#pragma unroll
    for (int ot = 0; ot < 4; ++ot) {
      bf16x8 bfrag = *(bf16x8*)&wlds[buf][(ot * 16 + (lane & 15)) * WSTRIDE + aq];
      acc[0][ot] = __builtin_amdgcn_mfma_f32_16x16x32_bf16(a0, bfrag, acc[0][ot], 0, 0, 0);
      acc[1][ot] = __builtin_amdgcn_mfma_f32_16x16x32_bf16(a1, bfrag, acc[1][ot], 0, 0, 0);
    }

    if (step + 1 < 32) {
      bf16x8 wv;
#pragma unroll
      for (int j = 0; j < 8; ++j) wv[j] = (bf16_t)fmaf((float)qr[j], sf, nzs);
      *(bf16x8*)&wlds[1 - buf][oq * WSTRIDE + kq] = wv;
    }
  }

  // epilogue: C/D layout col = lane&15, row = (lane>>4)*4 + r
#pragma unroll
  for (int mt = 0; mt < 2; ++mt) {
    const int m = w * 32 + mt * 16 + ((lane >> 4) << 2);
#pragma unroll
    for (int ot = 0; ot < 4; ++ot) {
      const int o = o0 + ot * 16 + (lane & 15);
#pragma unroll
      for (int r = 0; r < 4; ++r)
        unsafeAtomicAdd(&out[(size_t)(m + r) * N_OUT + o], acc[mt][ot][r]);
    }
  }
}

// ---------------------------------------------------------------------------
extern "C" void kernel_launch(void* const* d_in, const int* in_sizes, int n_in,
                              void* d_out, int out_size, void* d_ws, size_t ws_size,
                              hipStream_t stream) {
  const float* x = (const float*)d_in[0];
  const int* qw = (const int*)d_in[1];
  const int* zr = (const int*)d_in[2];
  const float* sc = (const float*)d_in[3];
  const float* loraA = (const float*)d_in[4];
  const float* loraB = (const float*)d_in[5];
  float* out = (float*)d_out;

  float* T = (float*)d_ws;                              // 128*16 fp32 = 8 KB
  bf16_t* xb = (bf16_t*)((char*)d_ws + 8192);           // 128*4096 bf16 = 1 MB

  k_prep<<<dim3(M_TOK), dim3(256), 0, stream>>>(x, loraA, T, xb);
  k_lora<<<dim3(M_TOK * 43), dim3(256), 0, stream>>>(T, loraB, out);
  k_main<<<dim3(NSTRIPS * 4), dim3(256), 0, stream>>>(qw, zr, sc, xb, out);
}

// Round 2
// 293.599 us; speedup vs baseline: 1.0171x; 1.0171x over previous
//
#include <hip/hip_runtime.h>
#include <hip/hip_bf16.h>

typedef __bf16 bf16_t;
typedef __bf16 bf16x8 __attribute__((ext_vector_type(8)));
typedef __bf16 bf16x4 __attribute__((ext_vector_type(4)));
typedef float f32x4 __attribute__((ext_vector_type(4)));

#define M_TOK 128
#define K_IN 4096
#define N_OUT 11008
#define R_LORA 16
#define SCALING 2.0f

// ---------------------------------------------------------------------------
// Kernel A: x (fp32) -> x_bf16 in ws, and T = (x @ lora_A^T) * SCALING in ws.
// ---------------------------------------------------------------------------
__global__ __launch_bounds__(256) void k_prep(const float* __restrict__ x,
                                              const float* __restrict__ loraA,
                                              float* __restrict__ T,
                                              bf16_t* __restrict__ xb) {
  const int m = blockIdx.x;
  __shared__ float xs[K_IN];
  const float4* xr = (const float4*)(x + (size_t)m * K_IN);
  bf16x4* xbr = (bf16x4*)(xb + (size_t)m * K_IN);
  for (int i = threadIdx.x; i < K_IN / 4; i += 256) {
    float4 v = xr[i];
    ((float4*)xs)[i] = v;
    bf16x4 pv = {(bf16_t)v.x, (bf16_t)v.y, (bf16_t)v.z, (bf16_t)v.w};
    xbr[i] = pv;
  }
  __syncthreads();
  const int w = threadIdx.x >> 6;
  const int lane = threadIdx.x & 63;
  float a0 = 0.f, a1 = 0.f, a2 = 0.f, a3 = 0.f;
  const float4* A0 = (const float4*)(loraA + (size_t)(w * 4 + 0) * K_IN);
  const float4* A1 = (const float4*)(loraA + (size_t)(w * 4 + 1) * K_IN);
  const float4* A2 = (const float4*)(loraA + (size_t)(w * 4 + 2) * K_IN);
  const float4* A3 = (const float4*)(loraA + (size_t)(w * 4 + 3) * K_IN);
  for (int i = lane; i < K_IN / 4; i += 64) {
    float4 xv = ((float4*)xs)[i];
    float4 v0 = A0[i], v1 = A1[i], v2 = A2[i], v3 = A3[i];
    a0 += xv.x * v0.x + xv.y * v0.y + xv.z * v0.z + xv.w * v0.w;
    a1 += xv.x * v1.x + xv.y * v1.y + xv.z * v1.z + xv.w * v1.w;
    a2 += xv.x * v2.x + xv.y * v2.y + xv.z * v2.z + xv.w * v2.w;
    a3 += xv.x * v3.x + xv.y * v3.y + xv.z * v3.z + xv.w * v3.w;
  }
#pragma unroll
  for (int off = 32; off; off >>= 1) {
    a0 += __shfl_down(a0, off);
    a1 += __shfl_down(a1, off);
    a2 += __shfl_down(a2, off);
    a3 += __shfl_down(a3, off);
  }
  if (lane == 0) {
    float* tm = T + m * R_LORA + w * 4;
    tm[0] = a0 * SCALING;
    tm[1] = a1 * SCALING;
    tm[2] = a2 * SCALING;
    tm[3] = a3 * SCALING;
  }
}

// ---------------------------------------------------------------------------
// Kernel B: out = T @ lora_B^T (full overwrite of d_out -> handles poison).
// ---------------------------------------------------------------------------
__global__ __launch_bounds__(256) void k_lora(const float* __restrict__ T,
                                              const float* __restrict__ loraB,
                                              float* __restrict__ out) {
  const int b = blockIdx.x;
  const int m = b / 43;
  const int o = (b % 43) * 256 + threadIdx.x;
  const float* t = T + m * R_LORA;
  const float4* br = (const float4*)(loraB + (size_t)o * R_LORA);
  float4 b0 = br[0], b1 = br[1], b2 = br[2], b3 = br[3];
  float s = t[0] * b0.x + t[1] * b0.y + t[2] * b0.z + t[3] * b0.w +
            t[4] * b1.x + t[5] * b1.y + t[6] * b1.z + t[7] * b1.w +
            t[8] * b2.x + t[9] * b2.y + t[10] * b2.z + t[11] * b2.w +
            t[12] * b3.x + t[13] * b3.y + t[14] * b3.z + t[15] * b3.w;
  out[(size_t)m * N_OUT + o] = s;
}

// ---------------------------------------------------------------------------
// Kernel C: main dequant GEMM. 172 N-strips (64 cols) x 4 K-chunks (1024).
// BK=64 per barrier step (16 steps). Per thread: 1 column, 16 k-rows/step.
// LDS [o][k], o-stride 72 bf16 = 144 B (stride/16B = 9, odd -> quads spread).
// Group (scale, -z*s) pairs fully hoisted; 16-step loop fully unrolled.
// ---------------------------------------------------------------------------
#define NSTRIPS 172
#define WSTRIDE 72  // bf16 elems per o-row in LDS (144 B)

__global__ __launch_bounds__(256, 4) void k_main(const int* __restrict__ qw,
                                                 const int* __restrict__ zr,
                                                 const float* __restrict__ sc,
                                                 const bf16_t* __restrict__ xb,
                                                 float* __restrict__ out) {
  const int nb = blockIdx.x % NSTRIPS;
  const int kc = blockIdx.x / NSTRIPS;  // 0..3
  const int o0 = nb * 64;
  const int k0 = kc * 1024;

  __shared__ __align__(16) bf16_t wlds[2][64 * WSTRIDE];  // 18432 B

  const int tid = threadIdx.x;
  const int w = tid >> 6;
  const int lane = tid & 63;
  const int oq = lane;          // staging column within tile
  const int kq = w * 16;        // staging k-base within 64-row step
  const int ocol = o0 + oq;
  const int* qp = qw + (size_t)(k0 + kq) * N_OUT + ocol;

  // hoist all 8 groups' dequant params for this column
  float sf[8], nzs[8];
  {
    const int g0 = k0 >> 7;
#pragma unroll
    for (int g = 0; g < 8; ++g) {
      float s_ = sc[(size_t)(g0 + g) * N_OUT + ocol];
      int z_ = zr[(size_t)(g0 + g) * N_OUT + ocol];
      sf[g] = s_;
      nzs[g] = -(float)z_ * s_;
    }
  }

  int qr[16];
#pragma unroll
  for (int j = 0; j < 16; ++j) qr[j] = qp[(size_t)j * N_OUT];
  {
    bf16x8 wv0, wv1;
#pragma unroll
    for (int j = 0; j < 8; ++j) {
      wv0[j] = (bf16_t)fmaf((float)qr[j], sf[0], nzs[0]);
      wv1[j] = (bf16_t)fmaf((float)qr[8 + j], sf[0], nzs[0]);
    }
    *(bf16x8*)&wlds[0][oq * WSTRIDE + kq] = wv0;
    *(bf16x8*)&wlds[0][oq * WSTRIDE + kq + 8] = wv1;
  }

  f32x4 acc[2][4];
#pragma unroll
  for (int mt = 0; mt < 2; ++mt)
#pragma unroll
    for (int ot = 0; ot < 4; ++ot) acc[mt][ot] = (f32x4){0.f, 0.f, 0.f, 0.f};

  // MFMA A-operand: lane holds A[m = lane&15][k = (lane>>4)*8 + j]
  const int aq = (lane >> 4) * 8;
  const bf16_t* ap = xb + (size_t)(w * 32 + (lane & 15)) * K_IN + k0 + aq;

#pragma unroll
  for (int step = 0; step < 16; ++step) {
    __syncthreads();
    const int buf = step & 1;

    if (step + 1 < 16) {
      const int* qn = qp + (size_t)(step + 1) * 64 * N_OUT;
#pragma unroll
      for (int j = 0; j < 16; ++j) qr[j] = qn[(size_t)j * N_OUT];
    }

#pragma unroll
    for (int ks = 0; ks < 2; ++ks) {
      bf16x8 a0 = *(const bf16x8*)(ap + step * 64 + ks * 32);
      bf16x8 a1 = *(const bf16x8*)(ap + (size_t)16 * K_IN + step * 64 + ks * 32);
#pragma unroll
      for (int ot = 0; ot < 4; ++ot) {
        bf16x8 bfrag =
            *(bf16x8*)&wlds[buf][(ot * 16 + (lane & 15)) * WSTRIDE + ks * 32 + aq];
        acc[0][ot] = __builtin_amdgcn_mfma_f32_16x16x32_bf16(a0, bfrag, acc[0][ot], 0, 0, 0);
        acc[1][ot] = __builtin_amdgcn_mfma_f32_16x16x32_bf16(a1, bfrag, acc[1][ot], 0, 0, 0);
      }
    }

    if (step + 1 < 16) {
      const int g = (step + 1) >> 1;  // 64 rows/step, 128 rows/group
      bf16x8 wv0, wv1;
#pragma unroll
      for (int j = 0; j < 8; ++j) {
        wv0[j] = (bf16_t)fmaf((float)qr[j], sf[g], nzs[g]);
        wv1[j] = (bf16_t)fmaf((float)qr[8 + j], sf[g], nzs[g]);
      }
      *(bf16x8*)&wlds[1 - buf][oq * WSTRIDE + kq] = wv0;
      *(bf16x8*)&wlds[1 - buf][oq * WSTRIDE + kq + 8] = wv1;
    }
  }

  // epilogue: C/D layout col = lane&15, row = (lane>>4)*4 + r
#pragma unroll
  for (int mt = 0; mt < 2; ++mt) {
    const int m = w * 32 + mt * 16 + ((lane >> 4) << 2);
#pragma unroll
    for (int ot = 0; ot < 4; ++ot) {
      const int o = o0 + ot * 16 + (lane & 15);
#pragma unroll
      for (int r = 0; r < 4; ++r)
        unsafeAtomicAdd(&out[(size_t)(m + r) * N_OUT + o], acc[mt][ot][r]);
    }
  }
}

// ---------------------------------------------------------------------------
extern "C" void kernel_launch(void* const* d_in, const int* in_sizes, int n_in,
                              void* d_out, int out_size, void* d_ws, size_t ws_size,
                              hipStream_t stream) {
  const float* x = (const float*)d_in[0];
  const int* qw = (const int*)d_in[1];
  const int* zr = (const int*)d_in[2];
  const float* sc = (const float*)d_in[3];
  const float* loraA = (const float*)d_in[4];
  const float* loraB = (const float*)d_in[5];
  float* out = (float*)d_out;

  float* T = (float*)d_ws;                     // 128*16 fp32 = 8 KB
  bf16_t* xb = (bf16_t*)((char*)d_ws + 8192);  // 128*4096 bf16 = 1 MB

  k_prep<<<dim3(M_TOK), dim3(256), 0, stream>>>(x, loraA, T, xb);
  k_lora<<<dim3(M_TOK * 43), dim3(256), 0, stream>>>(T, loraB, out);
  k_main<<<dim3(NSTRIPS * 4), dim3(256), 0, stream>>>(qw, zr, sc, xb, out);
}